// Round 6
// baseline (483.482 us; speedup 1.0000x reference)
//
#include <hip/hip_runtime.h>

typedef _Float16 half8 __attribute__((ext_vector_type(8)));
typedef _Float16 half4v __attribute__((ext_vector_type(4)));
typedef float floatx4 __attribute__((ext_vector_type(4)));
typedef float floatx16 __attribute__((ext_vector_type(16)));

#define GLD16(g, l) __builtin_amdgcn_global_load_lds(                          \
    (__attribute__((address_space(1))) void*)(g),                              \
    (__attribute__((address_space(3))) void*)(l), 16, 0, 0)

// ------------------------------------------------- fused fp32->fp16 casts (5)
__global__ void cvt_all(const float* __restrict__ s0, const float* __restrict__ s1,
                        const float* __restrict__ s2, const float* __restrict__ s3,
                        const float* __restrict__ s4, _Float16* __restrict__ d0,
                        _Float16* __restrict__ d1, _Float16* __restrict__ d2,
                        _Float16* __restrict__ d3, _Float16* __restrict__ d4) {
  long i = (long)blockIdx.x * 256 + threadIdx.x;  // float4-unit index
  const float* s;
  _Float16* d;
  long off;
  if (i < 2359296) { s = s0; d = d0; off = i; }
  else if (i < 3538944) { s = s1; d = d1; off = i - 2359296; }
  else if (i < 4128768) { s = s2; d = d2; off = i - 3538944; }
  else if (i < 4718592) { s = s3; d = d3; off = i - 4128768; }
  else { s = s4; d = d4; off = i - 4718592; }
  const float4 v = *(const float4*)(s + off * 4);
  half4v o = {(_Float16)v.x, (_Float16)v.y, (_Float16)v.z, (_Float16)v.w};
  *(half4v*)(d + off * 4) = o;
}

// ------------------------------------------------- GEMM C = A * B^T (NT form)
// Two-pipe operand split: A staged in LDS (GLD16, double-buffered, XOR
// swizzle); B fragments read DIRECTLY from global (L1/L2) - halves the LDS
// pipe traffic that was the R5 wall (64KB/block/K-step ~ 770cyc vs 256 MFMA).
// 32x32x16 MFMA, wave tile 64x64 (2x2), block 128x128, BK=64.
template <typename TO>
__global__ __launch_bounds__(256) void gemm_nt(const _Float16* __restrict__ A,
                                               const _Float16* __restrict__ B,
                                               TO* __restrict__ C, int M, int N,
                                               int K) {
  __shared__ __align__(16) _Float16 lA[2][128 * 64];
  const int tid = threadIdx.x;
  const int lane = tid & 63;
  const int w = tid >> 6;
  const int wm = w >> 1, wn = w & 1;
  const int l31 = lane & 31;
  const int kg = lane >> 5;  // k-group 0/1
  const long tM = (long)blockIdx.y * 128;
  const long tN = (long)blockIdx.x * 128;

  floatx16 acc[2][2] = {};

  const _Float16* Ab = A + tM * K;
  const _Float16* Bb = B + tN * K;
  // this wave's two B rows base pointers (rows wn*64 + j*32 + l31)
  const _Float16* Brow[2] = {Bb + (long)(wn * 64 + l31) * K,
                             Bb + (long)(wn * 64 + 32 + l31) * K};

  // A staging: U in [0,1024) = (row 0..127, unit 0..7 of 16B);
  // LDS slot (r,u) holds global unit u^(r&7) of row r (same 128B line).
  int sr[4], sc_[4];
#pragma unroll
  for (int p = 0; p < 4; ++p) {
    const int U = p * 256 + tid;
    sr[p] = U >> 3;
    sc_[p] = ((U & 7) ^ (sr[p] & 7)) << 3;
  }

#pragma unroll
  for (int p = 0; p < 4; ++p) {
    const int U = p * 256 + tid;
    GLD16(Ab + (long)sr[p] * K + sc_[p], &lA[0][U * 8]);
  }

  int cur = 0;
  for (int k0 = 0; k0 < K; k0 += 64) {
    __syncthreads();  // lA[cur] staged; lA[cur^1] reads done
    // issue ALL B-fragment gathers for this K-step first (VMEM pipe), so
    // their latency overlaps the LDS af reads + MFMA stream below
    half8 bf[4][2];
#pragma unroll
    for (int t = 0; t < 4; ++t) {
      const int g = t * 2 + kg;
#pragma unroll
      for (int j = 0; j < 2; ++j)
        bf[t][j] = *(const half8*)(Brow[j] + k0 + g * 8);
    }
    if (k0 + 64 < K) {  // stage next A tile into the other buffer
      const int nxt = cur ^ 1;
#pragma unroll
      for (int p = 0; p < 4; ++p) {
        const int U = p * 256 + tid;
        GLD16(Ab + (long)sr[p] * K + (k0 + 64 + sc_[p]), &lA[nxt][U * 8]);
      }
    }
#pragma unroll
    for (int t = 0; t < 4; ++t) {  // 4 k-steps of 16
      const int g = t * 2 + kg;
      half8 af[2];
#pragma unroll
      for (int i = 0; i < 2; ++i) {
        const int ra = wm * 64 + i * 32 + l31;
        af[i] = *(const half8*)&lA[cur][ra * 64 + ((g ^ (ra & 7)) << 3)];
      }
#pragma unroll
      for (int i = 0; i < 2; ++i)
#pragma unroll
        for (int j = 0; j < 2; ++j)
          acc[i][j] = __builtin_amdgcn_mfma_f32_32x32x16_f16(af[i], bf[t][j],
                                                             acc[i][j], 0, 0, 0);
    }
    cur ^= 1;
  }

#pragma unroll
  for (int i = 0; i < 2; ++i)
#pragma unroll
    for (int j = 0; j < 2; ++j) {
      const long col = tN + wn * 64 + j * 32 + l31;
#pragma unroll
      for (int reg = 0; reg < 16; ++reg) {
        const long row =
            tM + wm * 64 + i * 32 + (reg & 3) + 8 * (reg >> 2) + 4 * kg;
        C[row * N + col] = (TO)acc[i][j][reg];
      }
    }
}

// ----------------------------------------------------------------- RoPE q,k
__global__ void rope_qk(const _Float16* __restrict__ QKV,
                        const int* __restrict__ pos_ids,
                        _Float16* __restrict__ Qr, _Float16* __restrict__ Kr) {
  const int idx = blockIdx.x * blockDim.x + threadIdx.x;
  const int d = idx & 127;
  const int rest = idx >> 7;
  const int head = rest % 12;
  const int ms = rest / 12;
  const int s = ms & 2047;
  const int b = ms >> 11;
  const float ang = (float)pos_ids[s] * expf(d * -0.07195578164f);
  const float c = cosf(ang), sn = sinf(ang);
  if (head < 8) {
    const _Float16* src = QKV + (long)ms * 4096 + head * 256 + d;
    const float x1 = (float)src[0], x2 = (float)src[128];
    _Float16* dst = Qr + (((long)b * 8 + head) * 2048 + s) * 256 + d;
    dst[0] = (_Float16)(x1 * c - x2 * sn);
    dst[128] = (_Float16)(x2 * c + x1 * sn);
  } else {
    const int kh = head - 8;
    const _Float16* src = QKV + (long)ms * 4096 + 2048 + kh * 256 + d;
    const float x1 = (float)src[0], x2 = (float)src[128];
    _Float16* dst = Kr + (((long)b * 4 + kh) * 2048 + s) * 256 + d;
    dst[0] = (_Float16)(x1 * c - x2 * sn);
    dst[128] = (_Float16)(x2 * c + x1 * sn);
  }
}

// ------------------------------------------- V transpose: QKV -> Vt[b,kvh,d,s]
__global__ void vtrans(const _Float16* __restrict__ QKV,
                       _Float16* __restrict__ Vt) {
  __shared__ _Float16 lT[64 * 65];  // [s][d], +1-half pad
  const int tid = threadIdx.x;
  const int ss = blockIdx.x * 64;
  const int dd = blockIdx.y * 64;
  const int z = blockIdx.z;  // b*4+kvh
  const int b = z >> 2, kvh = z & 3;

#pragma unroll
  for (int pass = 0; pass < 2; ++pass) {
    const int U = pass * 256 + tid;
    const int s_loc = U >> 3, du = U & 7;
    const half8 v = *(const half8*)(QKV + ((long)(b * 2048 + ss + s_loc)) * 4096 +
                                    3072 + kvh * 256 + dd + du * 8);
#pragma unroll
    for (int e = 0; e < 8; ++e) lT[s_loc * 65 + du * 8 + e] = v[e];
  }
  __syncthreads();
#pragma unroll
  for (int pass = 0; pass < 2; ++pass) {
    const int U = pass * 256 + tid;
    const int su = U & 7, dl = (U >> 3) & 63;
    half8 o;
#pragma unroll
    for (int e = 0; e < 8; ++e) o[e] = lT[(su * 8 + e) * 65 + dl];
    *(half8*)(Vt + ((long)z * 256 + dd + dl) * 2048 + ss + su * 8) = o;
  }
}

// ------------------------------------------------------------ flash attention
// FIXED-SHIFT softmax (softcap bounds scores; P = exp(cap - 5) is exact
// softmax). Double-buffered lK; row-split QK, d-split PV; ones-MFMA denoms.
__global__ __launch_bounds__(256, 2) void attn_fwd(
    const _Float16* __restrict__ Q, const _Float16* __restrict__ K,
    const _Float16* __restrict__ Vt, _Float16* __restrict__ AO) {
  __shared__ __align__(16) _Float16 lK[2][64 * 256];  // XOR-swizzled units
  __shared__ __align__(16) _Float16 lP[64 * 76];      // [q-row][key], stride 76

  const int tid = threadIdx.x;
  const int lane = tid & 63;
  const int w = tid >> 6;
  const int quad = lane >> 4, l15 = lane & 15;

  const int qt = blockIdx.x;
  const int h = blockIdx.y;
  const int b = blockIdx.z;
  const int kvh = h >> 1;
  const int qs = qt * 64;

  const _Float16* Qb = Q + (((long)b * 8 + h) * 2048) * 256;
  const _Float16* Kb = K + (((long)b * 4 + kvh) * 2048) * 256;
  const _Float16* Vb = Vt + (((long)b * 4 + kvh) * 256) * 2048;

  half8 qf[8];
  {
    const _Float16* qp = Qb + (long)(qs + w * 16 + l15) * 256 + quad * 8;
#pragma unroll
    for (int t = 0; t < 8; ++t) qf[t] = *(const half8*)(qp + t * 32);
  }
  half8 onesv;
#pragma unroll
  for (int e = 0; e < 8; ++e) onesv[e] = (_Float16)1.f;

  floatx4 o[4][4] = {};  // rows i*16+quad*4+r, cols w*64 + j*16 + l15
  floatx4 lacc[4] = {};  // row sums (replicated over l15), rows i*16+quad*4+r

  const int kt_lo = qt >= 16 ? qt - 16 : 0;

  // prologue: stage first K tile into buffer 0
  {
    const _Float16* kt0 = Kb + (long)kt_lo * 64 * 256;
#pragma unroll
    for (int p = 0; p < 8; ++p) {
      const int U = p * 256 + tid;
      const int r = U >> 5, u = U & 31;
      GLD16(kt0 + r * 256 + ((u ^ (r & 7)) << 3), &lK[0][U * 8]);
    }
  }

  int cur = 0;
  for (int kt = kt_lo; kt <= qt; ++kt, cur ^= 1) {
    const int ks = kt * 64;
    __syncthreads();  // lK[cur] staged; prev iter's lP reads done

    // vf prefetch first (older than stage loads -> waiting on vf leaves the
    // next-tile staging in flight)
    half8 vf[2][4];
#pragma unroll
    for (int t2 = 0; t2 < 2; ++t2)
#pragma unroll
      for (int j = 0; j < 4; ++j) {
        const int d = w * 64 + j * 16 + l15;
        vf[t2][j] = *(const half8*)(Vb + (long)d * 2048 + ks + t2 * 32 + quad * 8);
      }
    if (kt < qt) {  // stage next K tile into the other buffer
      const _Float16* kt0 = Kb + (long)(ks + 64) * 256;
      const int nxt = cur ^ 1;
#pragma unroll
      for (int p = 0; p < 8; ++p) {
        const int U = p * 256 + tid;
        const int r = U >> 5, u = U & 31;
        GLD16(kt0 + r * 256 + ((u ^ (r & 7)) << 3), &lK[nxt][U * 8]);
      }
    }

    // S = Q K^T (wave's 16 rows x 64 keys)
    floatx4 sc[4] = {};
#pragma unroll
    for (int t = 0; t < 8; ++t)
#pragma unroll
      for (int j = 0; j < 4; ++j) {
        const half8 kf = *(const half8*)&lK[cur][(j * 16 + l15) * 256 +
                                                 (((t * 4 + quad) ^ (l15 & 7)) << 3)];
        sc[j] = __builtin_amdgcn_mfma_f32_16x16x32_f16(qf[t], kf, sc[j], 0, 0, 0);
      }

    // P = exp(softcap(s) - 5); masked -> 0.  (C-layout: row=quad*4+r,
    // col=j*16+l15.)  softcap poly: 50*tanh(s/50) = s*(1 - t^2/3 + 2t^4/15).
    const bool need_mask = (kt == qt) || (kt == qt - 16);
    const int qr0 = qs + w * 16 + quad * 4;
#pragma unroll
    for (int j = 0; j < 4; ++j) {
      const int key = ks + j * 16 + l15;
#pragma unroll
      for (int r = 0; r < 4; ++r) {
        const float s = sc[j][r] * 0.0625f;
        const float t2 = (s * 0.02f) * (s * 0.02f);
        const float cap = s * (1.f + t2 * (-0.33333333f + t2 * 0.13333333f));
        float p = __expf(cap - 5.f);
        if (need_mask) {
          const bool ok = (key <= qr0 + r) && (qr0 + r - key < 1024);
          p = ok ? p : 0.f;
        }
        lP[(w * 16 + quad * 4 + r) * 76 + j * 16 + l15] = (_Float16)p;
      }
    }
    __syncthreads();  // lP visible to all waves

    // O += P*V ; row sums += P*ones (no rescale: fixed shift)
#pragma unroll
    for (int t2 = 0; t2 < 2; ++t2) {
      half8 pf[4];
#pragma unroll
      for (int i = 0; i < 4; ++i)
        pf[i] = *(const half8*)&lP[(i * 16 + l15) * 76 + t2 * 32 + quad * 8];
#pragma unroll
      for (int i = 0; i < 4; ++i) {
        lacc[i] = __builtin_amdgcn_mfma_f32_16x16x32_f16(pf[i], onesv, lacc[i],
                                                         0, 0, 0);
#pragma unroll
        for (int j = 0; j < 4; ++j)
          o[i][j] = __builtin_amdgcn_mfma_f32_16x16x32_f16(pf[i], vf[t2][j],
                                                           o[i][j], 0, 0, 0);
      }
    }
  }

  _Float16* aop = AO + ((long)b * 2048 + qs) * 2048 + (long)h * 256;
#pragma unroll
  for (int i = 0; i < 4; ++i)
#pragma unroll
    for (int r = 0; r < 4; ++r) {
      const int row = i * 16 + quad * 4 + r;
      const float inv = 1.0f / lacc[i][r];
#pragma unroll
      for (int j = 0; j < 4; ++j)
        aop[(long)row * 2048 + w * 64 + j * 16 + l15] =
            (_Float16)(o[i][j][r] * inv);
    }
}

// ---------------------------------------------------------------------- host
extern "C" void kernel_launch(void* const* d_in, const int* in_sizes, int n_in,
                              void* d_out, int out_size, void* d_ws,
                              size_t ws_size, hipStream_t stream) {
  const float* hs = (const float*)d_in[0];
  const float* Wq = (const float*)d_in[1];
  const float* Wk = (const float*)d_in[2];
  const float* Wv = (const float*)d_in[3];
  const float* Wo = (const float*)d_in[4];
  const int* pos = (const int*)d_in[5];
  float* out = (float*)d_out;

  _Float16* Xf = (_Float16*)d_ws;            // 4096*2304
  _Float16* Wqkv = Xf + 4096L * 2304;        // 4096*2304
  _Float16* Wo16 = Wqkv + 4096L * 2304;      // 2304*2048
  _Float16* QKV = Wo16 + 2304L * 2048;       // 4096*4096
  _Float16* Qr = QKV + 4096L * 4096;         // 2*8*2048*256
  _Float16* Kr = Qr + 2L * 8 * 2048 * 256;   // 2*4*2048*256
  _Float16* Vt = Kr + 2L * 4 * 2048 * 256;   // 2*4*256*2048 (V^T)
  _Float16* AO = Xf;                         // alias: Xf dead after GEMM1

  cvt_all<<<dim3(23040), dim3(256), 0, stream>>>(
      hs, Wq, Wk, Wv, Wo, Xf, Wqkv, Wqkv + 2048L * 2304, Wqkv + 3072L * 2304,
      Wo16);

  gemm_nt<_Float16><<<dim3(32, 32), dim3(256), 0, stream>>>(Xf, Wqkv, QKV, 4096,
                                                            4096, 2304);
  rope_qk<<<dim3(2 * 2048 * 12 * 128 / 256), dim3(256), 0, stream>>>(QKV, pos,
                                                                     Qr, Kr);
  vtrans<<<dim3(32, 4, 8), dim3(256), 0, stream>>>(QKV, Vt);
  attn_fwd<<<dim3(32, 8, 2), dim3(256), 0, stream>>>(Qr, Kr, Vt, AO);
  gemm_nt<float><<<dim3(18, 32), dim3(256), 0, stream>>>(AO, Wo16, out, 4096,
                                                         2304, 2048);
}